// Round 3
// baseline (11502.946 us; speedup 1.0000x reference)
//
#include <hip/hip_runtime.h>

// GRUNet: 2-layer GRU (B=128, T=512, I=64, H=256) + ReLU + FC(256->2).
// Round 3: persistent cooperative kernel + DISTRIBUTED flag barrier.
//   Round-2 post-mortem: central atomic fetch_add serialized 256 WGs
//   (~17us/step). Replace with per-WG flags: arrival = 256 parallel
//   release-stores to distinct cachelines; wait = each of 256 threads
//   polls one WG's flag; then per-wave agent acquire fence.
//   Everything else identical to round 2 (isolate the barrier change).

namespace {
constexpr int kB = 128;
constexpr int kT = 512;
constexpr int kI = 64;
constexpr int kH = 256;

constexpr int BT = 32;              // batch rows per WG
constexpr int JT = 8;               // hidden units per WG
constexpr int PH = 260;             // LDS stride for 256-wide rows
constexpr int PX = 68;              // LDS stride for 64-wide rows
constexpr int NB = kB / BT;         // 4
constexpr int NJ = kH / JT;         // 32
constexpr int WPL = NB * NJ;        // 128 WGs per layer
constexpr int NWG = 2 * WPL;        // 256 total

constexpr int kLdsFloats = 3 * JT * (PH + PH);  // 12480 floats
constexpr int kFlagStride = 16;     // u32s -> 64B per flag line
}

__device__ __forceinline__ float sigf(float v) { return 1.0f / (1.0f + expf(-v)); }

// Distributed grid barrier, generation 'gen' (1-based, monotonic).
// flags: u32[NWG * kFlagStride], zero-initialized.
__device__ __forceinline__ void grid_bar(unsigned* flags, unsigned gen) {
  __syncthreads();   // all WG stores issued & vmcnt-drained (compiler emits waitcnt before s_barrier)
  if (threadIdx.x == 0) {
    // release: writes back this XCD's dirty L2 (our h stores), then flag store
    __hip_atomic_store(flags + (unsigned)blockIdx.x * kFlagStride, gen,
                       __ATOMIC_RELEASE, __HIP_MEMORY_SCOPE_AGENT);
  }
  // each thread polls one WG's flag (256 threads == 256 WGs), fully parallel
  unsigned* my = flags + (unsigned)threadIdx.x * kFlagStride;
  while (__hip_atomic_load(my, __ATOMIC_RELAXED, __HIP_MEMORY_SCOPE_AGENT) < gen) {
    __builtin_amdgcn_s_sleep(1);
  }
  __syncthreads();
  // acquire: invalidate local L2 so subsequent vectorized h loads see remote writes
  __builtin_amdgcn_fence(__ATOMIC_ACQUIRE, "agent");
}

// 3-gate dot: a[0..IDIM) (global) against LDS rows {g*JT+jj} for g=0,1,2.
template <int IDIM, int IPAD>
__device__ __forceinline__ void dot3(const float* __restrict__ a,
                                     const float* w, int jj,
                                     float& r0, float& r1, float& r2) {
  float s0 = 0.f, s1 = 0.f, s2 = 0.f;
  #pragma unroll 8
  for (int k = 0; k < IDIM; k += 4) {
    const float4 av = *(const float4*)(a + k);
    const float4 w0 = *(const float4*)(w + (0 * JT + jj) * IPAD + k);
    const float4 w1 = *(const float4*)(w + (1 * JT + jj) * IPAD + k);
    const float4 w2 = *(const float4*)(w + (2 * JT + jj) * IPAD + k);
    s0 += av.x * w0.x + av.y * w0.y + av.z * w0.z + av.w * w0.w;
    s1 += av.x * w1.x + av.y * w1.y + av.z * w1.z + av.w * w1.w;
    s2 += av.x * w2.x + av.y * w2.y + av.z * w2.z + av.w * w2.w;
  }
  r0 = s0; r1 = s1; r2 = s2;
}

__global__ __launch_bounds__(256, 1) void gru_persistent(
    const float* __restrict__ x,
    const float* __restrict__ wih0, const float* __restrict__ whh0,
    const float* __restrict__ bih0, const float* __restrict__ bhh0,
    const float* __restrict__ wih1, const float* __restrict__ whh1,
    const float* __restrict__ bih1, const float* __restrict__ bhh1,
    const float* __restrict__ fcw, const float* __restrict__ fcb,
    float* __restrict__ h0buf, float* __restrict__ h1buf,
    unsigned* flags, float* out)
{
  const int bid   = blockIdx.x;
  const int layer = bid >> 7;
  const int wid   = bid & (WPL - 1);
  const int tid   = threadIdx.x;

  const int b0 = (wid & (NB - 1)) * BT;
  const int j0 = (wid >> 2) * JT;

  const float* win = (layer == 0) ? wih0 : wih1;
  const float* whh = (layer == 0) ? whh0 : whh1;
  const float* bih = (layer == 0) ? bih0 : bih1;
  const float* bhh = (layer == 0) ? bhh0 : bhh1;
  const int idim = (layer == 0) ? kI : kH;
  const int ipad = (layer == 0) ? PX : PH;

  // ---- stage this WG's 24 weight rows into LDS (once) ----
  __shared__ float lds[kLdsFloats];
  float* w_in = lds;
  float* w_h  = lds + 3 * JT * ipad;
  {
    const int pr = idim / 4;
    for (int i = tid; i < 3 * JT * pr; i += 256) {
      const int r = i / pr, c = (i - r * pr) * 4;
      const int g = r / JT, jr = r - g * JT;
      *(float4*)(w_in + r * ipad + c) =
          *(const float4*)(win + (size_t)(g * kH + j0 + jr) * idim + c);
    }
    for (int i = tid; i < 3 * JT * 64; i += 256) {
      const int r = i / 64, c = (i - r * 64) * 4;
      const int g = r / JT, jr = r - g * JT;
      *(float4*)(w_h + r * PH + c) =
          *(const float4*)(whh + (size_t)(g * kH + j0 + jr) * kH + c);
    }
  }

  // ---- per-thread invariants ----
  const int jj = tid & (JT - 1);
  const int b  = tid >> 3;
  const int j  = j0 + jj;
  const int br = b0 + b;                 // global batch row

  const float br_r = bih[j]          + bhh[j];
  const float br_z = bih[kH + j]     + bhh[kH + j];
  const float bn_i = bih[2 * kH + j];
  const float bn_h = bhh[2 * kH + j];

  __syncthreads();

  // ---- 513 pipelined steps ----
  for (int s = 0; s <= kT; ++s) {
    const bool active = (layer == 0) ? (s < kT) : (s >= 1);
    if (active) {
      const int t = (layer == 0) ? s : (s - 1);
      const float* arow = (layer == 0)
          ? (x + (size_t)br * kT * kI + (size_t)t * kI)
          : (h0buf + (size_t)(t & 1) * kB * kH + (size_t)br * kH);
      const float* hrow = ((layer == 0)
          ? (h0buf + (size_t)((s + 1) & 1) * kB * kH)
          : (h1buf + (size_t)(s & 1) * kB * kH)) + (size_t)br * kH;
      float* hout = (layer == 0)
          ? (h0buf + (size_t)(s & 1) * kB * kH)
          : (h1buf + (size_t)((s - 1) & 1) * kB * kH);

      float xr, xz, xn, hr, hz, hn;
      if (layer == 0) dot3<kI, PX>(arow, w_in, jj, xr, xz, xn);
      else            dot3<kH, PH>(arow, w_in, jj, xr, xz, xn);
      dot3<kH, PH>(hrow, w_h, jj, hr, hz, hn);

      const float rr = sigf(xr + hr + br_r);
      const float zz = sigf(xz + hz + br_z);
      const float nn = tanhf(xn + bn_i + rr * (hn + bn_h));
      const float hp = hrow[j];
      hout[(size_t)br * kH + j] = (1.f - zz) * nn + zz * hp;
    }
    grid_bar(flags, (unsigned)(s + 1));
  }

  // ---- FC epilogue: out[b][o] = fc_b[o] + sum relu(h1(T-1)) * fc_w[o][:] ----
  if (bid == 0) {
    const int o = tid & 1, bb = tid >> 1;
    const float* hf = h1buf + (size_t)1 * kB * kH + (size_t)bb * kH;  // parity (T-1)&1 == 1
    const float* wr = fcw + (size_t)o * kH;
    float acc = fcb[o];
    #pragma unroll 8
    for (int k = 0; k < kH; k += 4) {
      const float4 hv = *(const float4*)(hf + k);
      const float4 wv = *(const float4*)(wr + k);
      acc += fmaxf(hv.x, 0.f) * wv.x + fmaxf(hv.y, 0.f) * wv.y +
             fmaxf(hv.z, 0.f) * wv.z + fmaxf(hv.w, 0.f) * wv.w;
    }
    out[bb * 2 + o] = acc;
  }
}

extern "C" void kernel_launch(void* const* d_in, const int* in_sizes, int n_in,
                              void* d_out, int out_size, void* d_ws, size_t ws_size,
                              hipStream_t stream) {
  const float* x    = (const float*)d_in[0];
  const float* wih0 = (const float*)d_in[1];
  const float* whh0 = (const float*)d_in[2];
  const float* bih0 = (const float*)d_in[3];
  const float* bhh0 = (const float*)d_in[4];
  const float* wih1 = (const float*)d_in[5];
  const float* whh1 = (const float*)d_in[6];
  const float* bih1 = (const float*)d_in[7];
  const float* bhh1 = (const float*)d_in[8];
  const float* fcw  = (const float*)d_in[9];
  const float* fcb  = (const float*)d_in[10];

  float* h0buf = (float*)d_ws;                   // [2][B][H]
  float* h1buf = h0buf + 2 * kB * kH;            // [2][B][H]
  unsigned* flags = (unsigned*)(h1buf + 2 * kB * kH);  // [NWG][16] u32, 64B lines
  float* out = (float*)d_out;

  // zero h(-1) double-buffers + flags every call (deterministic)
  hipMemsetAsync(d_ws, 0,
                 (size_t)(4 * kB * kH) * sizeof(float) +
                 (size_t)NWG * kFlagStride * sizeof(unsigned), stream);

  void* args[] = { &x, &wih0, &whh0, &bih0, &bhh0, &wih1, &whh1, &bih1, &bhh1,
                   &fcw, &fcb, &h0buf, &h1buf, &flags, &out };
  hipLaunchCooperativeKernel((void*)gru_persistent, dim3(NWG), dim3(256),
                             args, 0, stream);
}

// Round 5
// 3914.917 us; speedup vs baseline: 2.9382x; 2.9382x over previous
//
#include <hip/hip_runtime.h>

// GRUNet: 2-layer GRU (B=128, T=512, I=64, H=256) + ReLU + FC(256->2).
// Round 5: group-local persistent kernel, fixed launch + de-diverged waves.
//   - 8 groups x 32 WGs; group owns 16 batch rows end-to-end; WG owns 8
//     hidden units of BOTH layers; all weights in STATIC LDS (122 KB).
//   - PLAIN launch (no coop): 256 WGs x 1/CU = all resident structurally.
//   - 512 threads = 8 waves, role per wave (no divergence):
//       wave bit2 = layer, bit1 = family (input-dot vs hidden-dot),
//       bit0 = row half. SIMD pairs l0(480 fma) + l1(768 fma) waves.
//   - Family split: fam0 computes W_in.input partials (+ share of l0's
//     r/z h-dot for balance), fam1 computes W_hh.h partials and finishes
//     (n-gate's two dots kept separate as GRU semantics require).
//   - Cross-WG h exchange + flags: RELAXED agent-scope atomics (MALL-
//     coherent, no L2 wb/inv fences). Order via __syncthreads vmcnt drain.
//   - One group flag-barrier per step (32 flags, 64B lines).

namespace {
constexpr int kB = 128, kT = 512, kI = 64, kH = 256;
constexpr int kBH = kB * kH;

constexpr int NG = 8, GW = 32, RPG = 16, NWG = NG * GW;  // 256 WGs
constexpr int NT = 512;                                   // threads per WG

constexpr int P64 = 68, P256 = 260;  // padded LDS strides (1-bank-pass reads)

constexpr int O_W0IH = 0;                      // [24][P64]
constexpr int O_W0HH = O_W0IH + 24 * P64;      // [24][P256]
constexpr int O_W1IH = O_W0HH + 24 * P256;
constexpr int O_W1HH = O_W1IH + 24 * P256;
constexpr int O_HS0  = O_W1HH + 24 * P256;     // [RPG][P256] h0(s-1)
constexpr int O_HS1  = O_HS0 + RPG * P256;     // [RPG][P256] h1(s-2)
constexpr int O_XS   = O_HS1 + RPG * P256;     // [RPG][P64]  x_t
constexpr int O_PB   = O_XS + RPG * P64;       // [2][128][3] partials
constexpr int LDSF   = O_PB + 2 * 128 * 3;     // 30528 floats = 122112 B

constexpr int kFlagStride = 16;                // u32 -> 64 B per flag line
}

__device__ __forceinline__ float sigf(float v) { return 1.0f / (1.0f + expf(-v)); }
__device__ __forceinline__ float dot4(const float4 a, const float4 b) {
  return a.x * b.x + a.y * b.y + a.z * b.z + a.w * b.w;
}
#define F4(p) (*(const float4*)(p))

__global__ __launch_bounds__(NT, 2) void gru_persistent(
    const float* __restrict__ x,
    const float* __restrict__ wih0, const float* __restrict__ whh0,
    const float* __restrict__ bih0, const float* __restrict__ bhh0,
    const float* __restrict__ wih1, const float* __restrict__ whh1,
    const float* __restrict__ bih1, const float* __restrict__ bhh1,
    const float* __restrict__ fcw, const float* __restrict__ fcb,
    float* __restrict__ h0buf, float* __restrict__ h1buf,
    unsigned* flags, float* __restrict__ out)
{
  __shared__ float lds[LDSF];

  const int bid = blockIdx.x;
  const int g   = bid >> 5;           // group 0..7
  const int wg  = bid & (GW - 1);     // local WG 0..31
  const int tid = threadIdx.x;
  const int j0  = wg * 8;             // hidden-unit base (both layers)
  const int r0  = g * RPG;            // batch-row base

  // ---- stage all weights into LDS once ----
  for (int i = tid; i < 24 * 16; i += NT) {       // w0ih 24 x 64
    const int r = i >> 4, c = (i & 15) * 4, gg = r >> 3, u2 = r & 7;
    *(float4*)(lds + O_W0IH + r * P64 + c) =
        F4(wih0 + (size_t)(gg * kH + j0 + u2) * kI + c);
  }
  for (int i = tid; i < 24 * 64; i += NT) {       // 3 x (24 x 256)
    const int r = i >> 6, c = (i & 63) * 4, gg = r >> 3, u2 = r & 7;
    const size_t src = (size_t)(gg * kH + j0 + u2) * kH + c;
    *(float4*)(lds + O_W0HH + r * P256 + c) = F4(whh0 + src);
    *(float4*)(lds + O_W1IH + r * P256 + c) = F4(wih1 + src);
    *(float4*)(lds + O_W1HH + r * P256 + c) = F4(whh1 + src);
  }

  // ---- role decode: wave = lay(2) x fam(2) x rowhalf(2) ----
  const int lay = (tid >> 8) & 1;     // waves 0-3 layer0, 4-7 layer1
  const int fam = (tid >> 7) & 1;     // 0: input-family, 1: hidden-family
  const int t6  = tid & 63;
  const int row = ((tid >> 6) & 1) * 8 + (t6 >> 3);  // 0..15
  const int uu  = t6 & 7;                            // 0..7
  const int t7  = row * 8 + uu;                      // fam-partner-shared
  const int j   = j0 + uu;

  const float* bi = lay ? bih1 : bih0;
  const float* bh = lay ? bhh1 : bhh0;
  const float br_r = bi[j] + bh[j];
  const float br_z = bi[kH + j] + bh[kH + j];
  const float bn_i = bi[2 * kH + j];
  const float bn_h = bh[2 * kH + j];

  // loop-invariant LDS pointers
  const float* ax  = lds + O_XS  + row * P64;
  const float* ah0 = lds + O_HS0 + row * P256;
  const float* ah1 = lds + O_HS1 + row * P256;
  const float* w0i_r = lds + O_W0IH + (0 * 8 + uu) * P64;
  const float* w0i_z = lds + O_W0IH + (1 * 8 + uu) * P64;
  const float* w0i_n = lds + O_W0IH + (2 * 8 + uu) * P64;
  const float* w0h_r = lds + O_W0HH + (0 * 8 + uu) * P256;
  const float* w0h_z = lds + O_W0HH + (1 * 8 + uu) * P256;
  const float* w0h_n = lds + O_W0HH + (2 * 8 + uu) * P256;
  const float* w1x_r = (fam == 0) ? lds + O_W1IH + (0 * 8 + uu) * P256
                                  : lds + O_W1HH + (0 * 8 + uu) * P256;
  const float* w1x_z = (fam == 0) ? lds + O_W1IH + (1 * 8 + uu) * P256
                                  : lds + O_W1HH + (1 * 8 + uu) * P256;
  const float* w1x_n = (fam == 0) ? lds + O_W1IH + (2 * 8 + uu) * P256
                                  : lds + O_W1HH + (2 * 8 + uu) * P256;
  const float* a1 = (fam == 0) ? ah0 : ah1;

  unsigned* myflag = flags + (unsigned)((g << 5) + (tid & 31)) * kFlagStride;

  __syncthreads();

  // ---- 513 pipelined steps ----
  for (int s = 0; s <= kT; ++s) {
    // A) stage h0(s-1), h1(s-2), x_t (MALL-coherent atomic loads for h)
    {
      const float* h0p = h0buf + (size_t)((s + 1) & 1) * kBH;
      const float* h1p = h1buf + (size_t)(s & 1) * kBH;
      #pragma unroll
      for (int p = 0; p < 4; ++p) {
        const int i = tid + p * NT;          // 0..2047
        const int r = i >> 7, c = i & 127;   // u64 col within row
        const unsigned long long v0 = __hip_atomic_load(
            (const unsigned long long*)(h0p + (size_t)(r0 + r) * kH) + c,
            __ATOMIC_RELAXED, __HIP_MEMORY_SCOPE_AGENT);
        const unsigned long long v1 = __hip_atomic_load(
            (const unsigned long long*)(h1p + (size_t)(r0 + r) * kH) + c,
            __ATOMIC_RELAXED, __HIP_MEMORY_SCOPE_AGENT);
        float2 f0, f1;
        __builtin_memcpy(&f0, &v0, 8);
        __builtin_memcpy(&f1, &v1, 8);
        *(float2*)(lds + O_HS0 + r * P256 + c * 2) = f0;
        *(float2*)(lds + O_HS1 + r * P256 + c * 2) = f1;
      }
      if (s < kT && tid < 256) {
        const int r = tid >> 4, c4 = (tid & 15) * 4;
        *(float4*)(lds + O_XS + r * P64 + c4) =
            F4(x + (size_t)(r0 + r) * kT * kI + (size_t)s * kI + c4);
      }
    }
    __syncthreads();

    // B) family dots (wave-uniform branches)
    float p0 = 0.f, p1 = 0.f, p2 = 0.f;
    if (lay == 0) {
      if (fam == 0) {
        // full x-dots (r,z,n) + r/z h-dot chunks [0,36) for balance
        #pragma unroll
        for (int c = 0; c < 16; ++c) {
          const float4 a = F4(ax + c * 4);
          p0 += dot4(a, F4(w0i_r + c * 4));
          p1 += dot4(a, F4(w0i_z + c * 4));
          p2 += dot4(a, F4(w0i_n + c * 4));
        }
        #pragma unroll 6
        for (int c = 0; c < 36; ++c) {
          const float4 a = F4(ah0 + c * 4);
          p0 += dot4(a, F4(w0h_r + c * 4));
          p1 += dot4(a, F4(w0h_z + c * 4));
        }
      } else {
        // full n h-dot + r/z h-dot chunks [36,64)
        #pragma unroll 6
        for (int c = 0; c < 36; ++c)
          p2 += dot4(F4(ah0 + c * 4), F4(w0h_n + c * 4));
        #pragma unroll 7
        for (int c = 36; c < 64; ++c) {
          const float4 a = F4(ah0 + c * 4);
          p0 += dot4(a, F4(w0h_r + c * 4));
          p1 += dot4(a, F4(w0h_z + c * 4));
          p2 += dot4(a, F4(w0h_n + c * 4));
        }
      }
    } else {
      // l1: fam0 = W1ih . h0(s-1), fam1 = W1hh . h1(s-2)
      #pragma unroll 8
      for (int c = 0; c < 64; ++c) {
        const float4 a = F4(a1 + c * 4);
        p0 += dot4(a, F4(w1x_r + c * 4));
        p1 += dot4(a, F4(w1x_z + c * 4));
        p2 += dot4(a, F4(w1x_n + c * 4));
      }
    }
    if (fam == 0) {
      float* pb = lds + O_PB + (lay * 128 + t7) * 3;
      pb[0] = p0; pb[1] = p1; pb[2] = p2;
    }
    __syncthreads();

    // C) finish + publish h (fam1 only)
    const bool act = lay ? (s >= 1) : (s < kT);
    if (fam == 1 && act) {
      const float* pb = lds + O_PB + (lay * 128 + t7) * 3;
      const float rr = sigf(pb[0] + p0 + br_r);
      const float zz = sigf(pb[1] + p1 + br_z);
      const float nn = tanhf(pb[2] + bn_i + rr * (p2 + bn_h));
      const float hp = (lay ? ah1 : ah0)[j];
      const float hv = (1.f - zz) * nn + zz * hp;
      float* hout = lay ? (h1buf + (size_t)((s + 1) & 1) * kBH)
                        : (h0buf + (size_t)(s & 1) * kBH);
      __hip_atomic_store(hout + (size_t)(r0 + row) * kH + j, hv,
                         __ATOMIC_RELAXED, __HIP_MEMORY_SCOPE_AGENT);
    }
    __syncthreads();  // vmcnt(0) drain of all h stores before flag

    // D) group flag barrier
    if (tid == 0) {
      __hip_atomic_store(flags + (unsigned)bid * kFlagStride,
                         (unsigned)(s + 1),
                         __ATOMIC_RELAXED, __HIP_MEMORY_SCOPE_AGENT);
    }
    while (__hip_atomic_load(myflag, __ATOMIC_RELAXED,
                             __HIP_MEMORY_SCOPE_AGENT) < (unsigned)(s + 1)) {
      __builtin_amdgcn_s_sleep(1);
    }
    asm volatile("" ::: "memory");
    __syncthreads();
  }

  // ---- FC epilogue: group's WG0, wave-local kseg reduce (no syncthreads) ----
  if (wg == 0 && tid < 256) {
    const int rv = tid >> 4, o = (tid >> 3) & 1, ks = tid & 7;
    const float* hf = h1buf + (size_t)kBH + (size_t)(r0 + rv) * kH;  // h1(T-1), parity 1
    const float* wfc = fcw + (size_t)o * kH;
    float acc = 0.f;
    #pragma unroll 8
    for (int k = ks * 32; k < ks * 32 + 32; ++k) {
      const float hv = __hip_atomic_load(hf + k, __ATOMIC_RELAXED,
                                         __HIP_MEMORY_SCOPE_AGENT);
      acc += fmaxf(hv, 0.f) * wfc[k];
    }
    acc += __shfl_xor(acc, 1);
    acc += __shfl_xor(acc, 2);
    acc += __shfl_xor(acc, 4);
    if (ks == 0) out[(r0 + rv) * 2 + o] = acc + fcb[o];
  }
}

extern "C" void kernel_launch(void* const* d_in, const int* in_sizes, int n_in,
                              void* d_out, int out_size, void* d_ws, size_t ws_size,
                              hipStream_t stream) {
  const float* x    = (const float*)d_in[0];
  const float* wih0 = (const float*)d_in[1];
  const float* whh0 = (const float*)d_in[2];
  const float* bih0 = (const float*)d_in[3];
  const float* bhh0 = (const float*)d_in[4];
  const float* wih1 = (const float*)d_in[5];
  const float* whh1 = (const float*)d_in[6];
  const float* bih1 = (const float*)d_in[7];
  const float* bhh1 = (const float*)d_in[8];
  const float* fcw  = (const float*)d_in[9];
  const float* fcb  = (const float*)d_in[10];

  float* h0buf = (float*)d_ws;                         // [2][B][H]
  float* h1buf = h0buf + 2 * kBH;                      // [2][B][H]
  unsigned* flags = (unsigned*)(h1buf + 2 * kBH);      // [NWG][16] u32
  float* out = (float*)d_out;

  // zero h(-1) parities + flags every call (deterministic across replays)
  hipMemsetAsync(d_ws, 0,
                 (size_t)(4 * kBH) * sizeof(float) +
                 (size_t)NWG * kFlagStride * sizeof(unsigned), stream);

  gru_persistent<<<NWG, NT, 0, stream>>>(
      x, wih0, whh0, bih0, bhh0, wih1, whh1, bih1, bhh1,
      fcw, fcb, h0buf, h1buf, flags, out);
}

// Round 6
// 3779.474 us; speedup vs baseline: 3.0435x; 1.0358x over previous
//
#include <hip/hip_runtime.h>

// GRUNet: 2-layer GRU (B=128, T=512, I=64, H=256) + ReLU + FC(256->2).
// Round 6: REGISTER-RESIDENT WEIGHTS (weights never touch LDS).
//   - 8 groups x 32 WGs x 512 thr; group owns 16 rows; WG owns 8 units
//     of both layers. Wave role = (layer, family, rowhalf); lane =
//     (unit j 0..7, kseg 0..7). Lane holds 3 gates x 32-float weight
//     slice in 96 VGPRs (loaded once).
//   - Per step: lane reads activation chunks from LDS (broadcast x8,
//     conflict-free via kseg-stride 580 = 145 chunks == 1 mod 8),
//     FMAs vs reg weights, shfl_xor k-reduce, partials -> LDS,
//     256 finisher threads apply gates and publish h via MALL stores.
//   - l0 family split by k-chunks: fam0 = ih(K=64) + hh chunks 0-2,
//     fam1 = hh chunks 3-7 (480 FMA-instr each); l1 fam0 = ih(K=256),
//     fam1 = hh(K=256) (768 each). SIMD pairs one l0 + one l1 wave.
//   - n-gate ih/hh partials kept separate (slots xn, hn).
//   - Sync: 3 __syncthreads + one group flag round per step (MALL
//     relaxed atomics, no L2 wb/inv fences) — round-5 scheme.

namespace {
constexpr int kB = 128, kT = 512, kI = 64, kH = 256, kBH = kB * kH;
constexpr int NG = 8, GW = 32, RPG = 16, NWG = 256, NT = 512;

// activation stage: [kseg 8][row 16][32], row stride 36, kseg stride 580
constexpr int SRS = 36;
constexpr int SKS = 16 * SRS + 4;          // 580 floats; 145 chunks == 1 mod 8
constexpr int O_S0 = 0;                    // h0(s-1) stage
constexpr int O_S1 = O_S0 + 8 * SKS;       // h1(s-2) stage
constexpr int O_X  = O_S1 + 8 * SKS;       // x_t stage [16][68]
constexpr int O_PB = O_X + RPG * 68;       // partials [4 cells][16 rows][36]
constexpr int PBN  = 4 * 16 * 36;          // 2304
constexpr int LDSF = O_PB + PBN;           // 12672 floats = 49.5 KB

constexpr int kFlagStride = 16;            // u32 -> 64B flag lines
}

__device__ __forceinline__ float sigf(float v) { return 1.0f / (1.0f + expf(-v)); }
__device__ __forceinline__ float dot4(const float4 a, const float4 b) {
  return a.x * b.x + a.y * b.y + a.z * b.z + a.w * b.w;
}
__device__ __forceinline__ float red8(float v) {   // sum over kseg lanes (bits 3..5)
  v += __shfl_xor(v, 8);
  v += __shfl_xor(v, 16);
  v += __shfl_xor(v, 32);
  return v;
}
#define F4(p) (*(const float4*)(p))

__global__ __launch_bounds__(NT, 2) void gru_persistent(
    const float* __restrict__ x,
    const float* __restrict__ wih0, const float* __restrict__ whh0,
    const float* __restrict__ bih0, const float* __restrict__ bhh0,
    const float* __restrict__ wih1, const float* __restrict__ whh1,
    const float* __restrict__ bih1, const float* __restrict__ bhh1,
    const float* __restrict__ fcw, const float* __restrict__ fcb,
    float* __restrict__ h0buf, float* __restrict__ h1buf,
    unsigned* flags, float* __restrict__ out)
{
  __shared__ float lds[LDSF];

  const int bid = blockIdx.x;
  const int g   = bid >> 5;            // group 0..7
  const int wg  = bid & (GW - 1);      // 0..31
  const int tid = threadIdx.x;
  const int r0  = g * RPG;
  const int j0  = wg * 8;

  const int wave = tid >> 6;           // 0..7
  const int lane = tid & 63;
  const int lay  = wave >> 2;          // 0,1
  const int fam  = (wave >> 1) & 1;    // 0: input-family, 1: hidden-family
  const int rh   = wave & 1;           // row half
  const int ju   = lane & 7;           // unit 0..7
  const int ks   = lane >> 3;          // kseg 0..7
  const int jg   = j0 + ju;            // global unit

  // zero partial buffer (unwritten slots must stay 0 forever)
  for (int i = tid; i < PBN; i += NT) lds[O_PB + i] = 0.f;

  // ---- load weight slices into registers (once) ----
  float4 wr0[8], wr1[8], wr2[8];
  if (lay == 0) {
    if (fam == 0) {
#define L0F0(wrg, gg) { \
      const float* wi = wih0 + (size_t)((gg) * kH + jg) * kI + ks * 8;   \
      const float* wh = whh0 + (size_t)((gg) * kH + jg) * kH + ks * 32;  \
      wrg[0] = F4(wi); wrg[1] = F4(wi + 4);                              \
      wrg[2] = F4(wh); wrg[3] = F4(wh + 4); wrg[4] = F4(wh + 8); }
      L0F0(wr0, 0) L0F0(wr1, 1) L0F0(wr2, 2)
    } else {
#define L0F1(wrg, gg) { \
      const float* wh = whh0 + (size_t)((gg) * kH + jg) * kH + ks * 32 + 12; \
      wrg[0] = F4(wh); wrg[1] = F4(wh + 4); wrg[2] = F4(wh + 8);             \
      wrg[3] = F4(wh + 12); wrg[4] = F4(wh + 16); }
      L0F1(wr0, 0) L0F1(wr1, 1) L0F1(wr2, 2)
    }
  } else {
    const float* ws = fam ? whh1 : wih1;
#define L1W(wrg, gg) { \
    const float* wp = ws + (size_t)((gg) * kH + jg) * kH + ks * 32;          \
    wrg[0] = F4(wp);      wrg[1] = F4(wp + 4);  wrg[2] = F4(wp + 8);         \
    wrg[3] = F4(wp + 12); wrg[4] = F4(wp + 16); wrg[5] = F4(wp + 20);        \
    wrg[6] = F4(wp + 24); wrg[7] = F4(wp + 28); }
    L1W(wr0, 0) L1W(wr1, 1) L1W(wr2, 2)
  }

  // ---- finisher-role constants (threads 0..255) ----
  float fb_r = 0.f, fb_z = 0.f, fb_ni = 0.f, fb_nh = 0.f;
  if (tid < 256) {
    const int layf = tid >> 7, uf = tid & 7, jf = j0 + uf;
    const float* bi = layf ? bih1 : bih0;
    const float* bh = layf ? bhh1 : bhh0;
    fb_r  = bi[jf] + bh[jf];
    fb_z  = bi[kH + jf] + bh[kH + jf];
    fb_ni = bi[2 * kH + jf];
    fb_nh = bh[2 * kH + jf];
  }

  unsigned* myflag = flags + (unsigned)((g << 5) + (tid & 31)) * kFlagStride;

  __syncthreads();

  // ---- 513 pipelined steps ----
  for (int s = 0; s <= kT; ++s) {
    // 1) stage h0(s-1), h1(s-2) into [kseg][row][32]; x_t into [row][68]
    {
      const float* h0p = h0buf + (size_t)((s + 1) & 1) * kBH;
      const float* h1p = h1buf + (size_t)(s & 1) * kBH;
      #pragma unroll
      for (int p = 0; p < 4; ++p) {
        const int i  = tid + p * NT;          // 0..2047
        const int ro = i >> 7, k2 = i & 127;  // u64 index in row
        const int k  = k2 * 2, ksg = k >> 5, off = k & 31;
        const unsigned long long v0 = __hip_atomic_load(
            (const unsigned long long*)(h0p + (size_t)(r0 + ro) * kH) + k2,
            __ATOMIC_RELAXED, __HIP_MEMORY_SCOPE_AGENT);
        const unsigned long long v1 = __hip_atomic_load(
            (const unsigned long long*)(h1p + (size_t)(r0 + ro) * kH) + k2,
            __ATOMIC_RELAXED, __HIP_MEMORY_SCOPE_AGENT);
        float2 f0, f1;
        __builtin_memcpy(&f0, &v0, 8);
        __builtin_memcpy(&f1, &v1, 8);
        *(float2*)(lds + O_S0 + ksg * SKS + ro * SRS + off) = f0;
        *(float2*)(lds + O_S1 + ksg * SKS + ro * SRS + off) = f1;
      }
      if (s < kT && tid < 256) {
        const int ro = tid >> 4, c4 = (tid & 15) * 4;
        *(float4*)(lds + O_X + ro * 68 + c4) =
            F4(x + (size_t)(r0 + ro) * kT * kI + (size_t)s * kI + c4);
      }
    }
    __syncthreads();

    // 2) dot phase (reg weights vs broadcast LDS activations)
    const bool wact = lay ? (s >= 1) : (s < kT);
    if (wact) {
      float prr[8], pzz[8], pni[8], pnh[8];
      #pragma unroll
      for (int r = 0; r < 8; ++r) {
        const int ro = rh * 8 + r;
        float pr = 0.f, pz = 0.f, pxi = 0.f, pxh = 0.f;
        if (lay == 0) {
          if (fam == 0) {
            const float* ax = lds + O_X + ro * 68 + ks * 8;
            const float4 x0 = F4(ax), x1 = F4(ax + 4);
            pr  += dot4(x0, wr0[0]) + dot4(x1, wr0[1]);
            pz  += dot4(x0, wr1[0]) + dot4(x1, wr1[1]);
            pxi += dot4(x0, wr2[0]) + dot4(x1, wr2[1]);
            const float* ah = lds + O_S0 + ks * SKS + ro * SRS;
            #pragma unroll
            for (int i = 0; i < 3; ++i) {
              const float4 hv = F4(ah + i * 4);
              pr  += dot4(hv, wr0[2 + i]);
              pz  += dot4(hv, wr1[2 + i]);
              pxh += dot4(hv, wr2[2 + i]);
            }
          } else {
            const float* ah = lds + O_S0 + ks * SKS + ro * SRS + 12;
            #pragma unroll
            for (int i = 0; i < 5; ++i) {
              const float4 hv = F4(ah + i * 4);
              pr  += dot4(hv, wr0[i]);
              pz  += dot4(hv, wr1[i]);
              pxh += dot4(hv, wr2[i]);
            }
          }
        } else {
          const float* aa = lds + (fam ? O_S1 : O_S0) + ks * SKS + ro * SRS;
          #pragma unroll
          for (int i = 0; i < 8; ++i) {
            const float4 av = F4(aa + i * 4);
            pr += dot4(av, wr0[i]);
            pz += dot4(av, wr1[i]);
            if (fam) pxh += dot4(av, wr2[i]);
            else     pxi += dot4(av, wr2[i]);
          }
        }
        prr[r] = pr; pzz[r] = pz; pni[r] = pxi; pnh[r] = pxh;
      }
      // k-reduction across kseg lanes (32 independent chains, pipelined)
      #pragma unroll
      for (int r = 0; r < 8; ++r) { prr[r] = red8(prr[r]); pzz[r] = red8(pzz[r]); }
      if (lay == 0 && fam == 0) {
        #pragma unroll
        for (int r = 0; r < 8; ++r) { pni[r] = red8(pni[r]); pnh[r] = red8(pnh[r]); }
      } else if (fam == 0) {
        #pragma unroll
        for (int r = 0; r < 8; ++r) pni[r] = red8(pni[r]);
      } else {
        #pragma unroll
        for (int r = 0; r < 8; ++r) pnh[r] = red8(pnh[r]);
      }
      if (ks == 0) {
        #pragma unroll
        for (int r = 0; r < 8; ++r) {
          float* pb = lds + O_PB + ((wave >> 1) * 16 + rh * 8 + r) * SRS + ju;
          pb[0] = prr[r]; pb[8] = pzz[r];
          if (lay == 0 && fam == 0) { pb[16] = pni[r]; pb[24] = pnh[r]; }
          else if (fam == 0)          pb[16] = pni[r];
          else                        pb[24] = pnh[r];
        }
      }
    }
    __syncthreads();

    // 3) finish: gates + publish h (256 threads)
    if (tid < 256) {
      const int layf = tid >> 7;
      const bool act = layf ? (s >= 1) : (s < kT);
      if (act) {
        const int rof = (tid >> 3) & 15, uf = tid & 7, jf = j0 + uf;
        const float* p0 = lds + O_PB + ((layf * 2) * 16 + rof) * SRS + uf;
        const float* p1 = p0 + 16 * SRS;
        const float rr = sigf(p0[0] + p1[0] + fb_r);
        const float zz = sigf(p0[8] + p1[8] + fb_z);
        const float nn = tanhf(p0[16] + p1[16] + fb_ni +
                               rr * (p0[24] + p1[24] + fb_nh));
        const float hp = lds[(layf ? O_S1 : O_S0) +
                             (jf >> 5) * SKS + rof * SRS + (jf & 31)];
        const float hv = (1.f - zz) * nn + zz * hp;
        float* hout = layf ? (h1buf + (size_t)((s + 1) & 1) * kBH)
                           : (h0buf + (size_t)(s & 1) * kBH);
        __hip_atomic_store(hout + (size_t)(r0 + rof) * kH + jf, hv,
                           __ATOMIC_RELAXED, __HIP_MEMORY_SCOPE_AGENT);
      }
    }
    __syncthreads();   // vmcnt(0) drain of h stores before flag

    // 4) group flag barrier (MALL relaxed atomics)
    if (tid == 0) {
      __hip_atomic_store(flags + (unsigned)bid * kFlagStride,
                         (unsigned)(s + 1),
                         __ATOMIC_RELAXED, __HIP_MEMORY_SCOPE_AGENT);
    }
    while (__hip_atomic_load(myflag, __ATOMIC_RELAXED,
                             __HIP_MEMORY_SCOPE_AGENT) < (unsigned)(s + 1)) {
      __builtin_amdgcn_s_sleep(1);
    }
    asm volatile("" ::: "memory");
  }

  // ---- FC epilogue: group's WG0 handles its 16 rows ----
  if (wg == 0 && tid < 256) {
    const int rv = tid >> 4, o = (tid >> 3) & 1, kseg = tid & 7;
    const float* hf = h1buf + (size_t)kBH + (size_t)(r0 + rv) * kH;  // h1(T-1), parity 1
    const float* wfc = fcw + (size_t)o * kH;
    float acc = 0.f;
    #pragma unroll 8
    for (int k = kseg * 32; k < kseg * 32 + 32; ++k) {
      const float hv = __hip_atomic_load(hf + k, __ATOMIC_RELAXED,
                                         __HIP_MEMORY_SCOPE_AGENT);
      acc += fmaxf(hv, 0.f) * wfc[k];
    }
    acc += __shfl_xor(acc, 1);
    acc += __shfl_xor(acc, 2);
    acc += __shfl_xor(acc, 4);
    if (kseg == 0) out[(r0 + rv) * 2 + o] = acc + fcb[o];
  }
}

extern "C" void kernel_launch(void* const* d_in, const int* in_sizes, int n_in,
                              void* d_out, int out_size, void* d_ws, size_t ws_size,
                              hipStream_t stream) {
  const float* x    = (const float*)d_in[0];
  const float* wih0 = (const float*)d_in[1];
  const float* whh0 = (const float*)d_in[2];
  const float* bih0 = (const float*)d_in[3];
  const float* bhh0 = (const float*)d_in[4];
  const float* wih1 = (const float*)d_in[5];
  const float* whh1 = (const float*)d_in[6];
  const float* bih1 = (const float*)d_in[7];
  const float* bhh1 = (const float*)d_in[8];
  const float* fcw  = (const float*)d_in[9];
  const float* fcb  = (const float*)d_in[10];

  float* h0buf = (float*)d_ws;                         // [2][B][H]
  float* h1buf = h0buf + 2 * kBH;                      // [2][B][H]
  unsigned* flags = (unsigned*)(h1buf + 2 * kBH);      // [NWG][16] u32
  float* out = (float*)d_out;

  // zero h(-1) parities + flags (deterministic across replays)
  hipMemsetAsync(d_ws, 0,
                 (size_t)(4 * kBH) * sizeof(float) +
                 (size_t)NWG * kFlagStride * sizeof(unsigned), stream);

  gru_persistent<<<NWG, NT, 0, stream>>>(
      x, wih0, whh0, bih0, bhh0, wih1, whh1, bih1, bhh1,
      fcw, fcb, h0buf, h1buf, flags, out);
}

// Round 7
// 3469.583 us; speedup vs baseline: 3.3154x; 1.0893x over previous
//
#include <hip/hip_runtime.h>

// GRUNet: 2-layer GRU (B=128, T=512, I=64, H=256) + ReLU + FC(256->2).
// Round 7: SELF-SYNCHRONIZING h-exchange (tag-in-mantissa dataflow).
//   - Round-6 structure kept: 8 groups x 32 WGs x 512 thr; register-
//     resident weights; lane=(unit,kseg); shfl_xor k-reduce; LDS partials.
//   - NEW: no flag barrier. h elements carry a 2-bit generation tag in
//     the 2 mantissa LSBs (rel. err <= 2^-21). 3 rotating slots per h
//     buffer; tag cycle 4 > live window 3 -> every reuse distinguishable.
//     Consumers sweep-poll the data directly (8 parallel u64 loads,
//     retry whole sweep on any tag miss) -> ONE MALL round-trip/step.
//   - WAR on slot reuse (+3 steps) guarded by lagging stage_done flags
//     checked against step s-2 (2-step slack -> off critical path).
//   - All cross-WG traffic: relaxed agent-scope atomics (MALL-coherent,
//     no L2 wb/inv fences) — validated rounds 5/6.

namespace {
constexpr int kB = 128, kT = 512, kI = 64, kH = 256, kBH = kB * kH;
constexpr int NG = 8, GW = 32, RPG = 16, NWG = 256, NT = 512;

// activation stage: [kseg 8][row 16][32], row stride 36, kseg stride 580
constexpr int SRS = 36;
constexpr int SKS = 16 * SRS + 4;          // 580
constexpr int O_S0 = 0;
constexpr int O_S1 = O_S0 + 8 * SKS;
constexpr int O_X  = O_S1 + 8 * SKS;
constexpr int O_PB = O_X + RPG * 68;
constexpr int PBN  = 4 * 16 * 36;
constexpr int LDSF = O_PB + PBN;           // 12672 floats = 49.5 KB

constexpr int FS = 16;                     // stage_done flag stride (64B)
}

using ull = unsigned long long;

__device__ __forceinline__ float sigf(float v) { return 1.0f / (1.0f + expf(-v)); }
__device__ __forceinline__ float dot4(const float4 a, const float4 b) {
  return a.x * b.x + a.y * b.y + a.z * b.z + a.w * b.w;
}
__device__ __forceinline__ float red8(float v) {   // sum over kseg lanes (bits 3..5)
  v += __shfl_xor(v, 8);
  v += __shfl_xor(v, 16);
  v += __shfl_xor(v, 32);
  return v;
}
#define F4(p) (*(const float4*)(p))

__global__ __launch_bounds__(NT, 2) void gru_persistent(
    const float* __restrict__ x,
    const float* __restrict__ wih0, const float* __restrict__ whh0,
    const float* __restrict__ bih0, const float* __restrict__ bhh0,
    const float* __restrict__ wih1, const float* __restrict__ whh1,
    const float* __restrict__ bih1, const float* __restrict__ bhh1,
    const float* __restrict__ fcw, const float* __restrict__ fcb,
    unsigned* __restrict__ h0w,    // [3][B][H] tagged dwords
    unsigned* __restrict__ h1w,    // [3][B][H] tagged dwords
    unsigned* __restrict__ sd,     // [NWG][FS] stage_done flags
    float* __restrict__ out)
{
  __shared__ float lds[LDSF];

  const int bid = blockIdx.x;
  const int g   = bid >> 5;            // group 0..7
  const int wg  = bid & (GW - 1);      // 0..31
  const int tid = threadIdx.x;
  const int r0  = g * RPG;
  const int j0  = wg * 8;

  const int wave = tid >> 6;           // 0..7
  const int lane = tid & 63;
  const int lay  = wave >> 2;          // 0,1
  const int fam  = (wave >> 1) & 1;
  const int rh   = wave & 1;
  const int ju   = lane & 7;
  const int ks   = lane >> 3;
  const int jg   = j0 + ju;

  for (int i = tid; i < PBN; i += NT) lds[O_PB + i] = 0.f;

  // ---- weight slices into registers (once) ----
  float4 wr0[8], wr1[8], wr2[8];
  if (lay == 0) {
    if (fam == 0) {
#define L0F0(wrg, gg) { \
      const float* wi = wih0 + (size_t)((gg) * kH + jg) * kI + ks * 8;   \
      const float* wh = whh0 + (size_t)((gg) * kH + jg) * kH + ks * 32;  \
      wrg[0] = F4(wi); wrg[1] = F4(wi + 4);                              \
      wrg[2] = F4(wh); wrg[3] = F4(wh + 4); wrg[4] = F4(wh + 8); }
      L0F0(wr0, 0) L0F0(wr1, 1) L0F0(wr2, 2)
    } else {
#define L0F1(wrg, gg) { \
      const float* wh = whh0 + (size_t)((gg) * kH + jg) * kH + ks * 32 + 12; \
      wrg[0] = F4(wh); wrg[1] = F4(wh + 4); wrg[2] = F4(wh + 8);             \
      wrg[3] = F4(wh + 12); wrg[4] = F4(wh + 16); }
      L0F1(wr0, 0) L0F1(wr1, 1) L0F1(wr2, 2)
    }
  } else {
    const float* ws = fam ? whh1 : wih1;
#define L1W(wrg, gg) { \
    const float* wp = ws + (size_t)((gg) * kH + jg) * kH + ks * 32;          \
    wrg[0] = F4(wp);      wrg[1] = F4(wp + 4);  wrg[2] = F4(wp + 8);         \
    wrg[3] = F4(wp + 12); wrg[4] = F4(wp + 16); wrg[5] = F4(wp + 20);        \
    wrg[6] = F4(wp + 24); wrg[7] = F4(wp + 28); }
    L1W(wr0, 0) L1W(wr1, 1) L1W(wr2, 2)
  }

  // ---- finisher constants (threads 0..255) ----
  float fb_r = 0.f, fb_z = 0.f, fb_ni = 0.f, fb_nh = 0.f;
  if (tid < 256) {
    const int layf = tid >> 7, uf = tid & 7, jf = j0 + uf;
    const float* bi = layf ? bih1 : bih0;
    const float* bh = layf ? bhh1 : bhh0;
    fb_r  = bi[jf] + bh[jf];
    fb_z  = bi[kH + jf] + bh[kH + jf];
    fb_ni = bi[2 * kH + jf];
    fb_nh = bh[2 * kH + jf];
  }

  // staging element indices (4 u64 per buffer per thread)
  int RO[4], K2[4];
  #pragma unroll
  for (int p = 0; p < 4; ++p) {
    const int i = tid + p * NT;          // 0..2047
    RO[p] = i >> 7; K2[p] = i & 127;
  }

  __syncthreads();

  // ---- 513 steps, no barrier: data-tag dataflow sync ----
  for (int s = 0; s <= kT; ++s) {
    const int slot0 = (s + 2) % 3;           // h0(s-1)
    const int slot1 = (s + 1) % 3;           // h1(s-2)
    const unsigned e0 = (unsigned)(s & 3);   // tag of h0(s-1) = ((s-1)+1)&3
    const unsigned e1 = (unsigned)((s - 1) & 3);

    // x stage first (independent plain loads)
    if (s < kT && tid < 256) {
      const int ro = tid >> 4, c4 = (tid & 15) * 4;
      *(float4*)(lds + O_X + ro * 68 + c4) =
          F4(x + (size_t)(r0 + ro) * kT * kI + (size_t)s * kI + c4);
    }
    // WAR guard: writers of step s reuse the slot read at step s-2;
    // require all group WGs to have finished staging of s-2 (value s-1).
    if (s >= 2 && tid >= 480) {
      const unsigned* f = sd + (unsigned)((g << 5) + (tid - 480)) * FS;
      while (__hip_atomic_load(f, __ATOMIC_RELAXED, __HIP_MEMORY_SCOPE_AGENT)
             < (unsigned)(s - 1)) { }
    }

    // sweep-poll h data (8 parallel u64 loads, retry sweep on tag miss)
    ull v0[4], v1[4];
    {
      const ull* A0[4]; const ull* A1[4];
      #pragma unroll
      for (int p = 0; p < 4; ++p) {
        A0[p] = (const ull*)(h0w + (size_t)slot0 * kBH +
                             (size_t)(r0 + RO[p]) * kH) + K2[p];
        A1[p] = (const ull*)(h1w + (size_t)slot1 * kBH +
                             (size_t)(r0 + RO[p]) * kH) + K2[p];
      }
      for (;;) {
        #pragma unroll
        for (int p = 0; p < 4; ++p)
          v0[p] = __hip_atomic_load(A0[p], __ATOMIC_RELAXED,
                                    __HIP_MEMORY_SCOPE_AGENT);
        if (s >= 1) {
          #pragma unroll
          for (int p = 0; p < 4; ++p)
            v1[p] = __hip_atomic_load(A1[p], __ATOMIC_RELAXED,
                                      __HIP_MEMORY_SCOPE_AGENT);
        }
        unsigned bad = 0;
        #pragma unroll
        for (int p = 0; p < 4; ++p)
          bad |= ((unsigned)v0[p] ^ e0) | ((unsigned)(v0[p] >> 32) ^ e0);
        if (s >= 1) {
          #pragma unroll
          for (int p = 0; p < 4; ++p)
            bad |= ((unsigned)v1[p] ^ e1) | ((unsigned)(v1[p] >> 32) ^ e1);
        }
        if (!(bad & 3u)) break;
      }
    }
    // unpack into LDS stage
    #pragma unroll
    for (int p = 0; p < 4; ++p) {
      const int ksg = K2[p] >> 4, off = (K2[p] * 2) & 31, ro = RO[p];
      float2 f0; __builtin_memcpy(&f0, &v0[p], 8);
      *(float2*)(lds + O_S0 + ksg * SKS + ro * SRS + off) = f0;
      if (s >= 1) {
        float2 f1; __builtin_memcpy(&f1, &v1[p], 8);
        *(float2*)(lds + O_S1 + ksg * SKS + ro * SRS + off) = f1;
      }
    }
    __syncthreads();
    if (tid == 0) {
      __hip_atomic_store(sd + (unsigned)bid * FS, (unsigned)(s + 1),
                         __ATOMIC_RELAXED, __HIP_MEMORY_SCOPE_AGENT);
    }

    // dot phase (unchanged from round 6)
    const bool wact = lay ? (s >= 1) : (s < kT);
    if (wact) {
      float prr[8], pzz[8], pni[8], pnh[8];
      #pragma unroll
      for (int r = 0; r < 8; ++r) {
        const int ro = rh * 8 + r;
        float pr = 0.f, pz = 0.f, pxi = 0.f, pxh = 0.f;
        if (lay == 0) {
          if (fam == 0) {
            const float* ax = lds + O_X + ro * 68 + ks * 8;
            const float4 x0 = F4(ax), x1 = F4(ax + 4);
            pr  += dot4(x0, wr0[0]) + dot4(x1, wr0[1]);
            pz  += dot4(x0, wr1[0]) + dot4(x1, wr1[1]);
            pxi += dot4(x0, wr2[0]) + dot4(x1, wr2[1]);
            const float* ah = lds + O_S0 + ks * SKS + ro * SRS;
            #pragma unroll
            for (int i = 0; i < 3; ++i) {
              const float4 hv = F4(ah + i * 4);
              pr  += dot4(hv, wr0[2 + i]);
              pz  += dot4(hv, wr1[2 + i]);
              pxh += dot4(hv, wr2[2 + i]);
            }
          } else {
            const float* ah = lds + O_S0 + ks * SKS + ro * SRS + 12;
            #pragma unroll
            for (int i = 0; i < 5; ++i) {
              const float4 hv = F4(ah + i * 4);
              pr  += dot4(hv, wr0[i]);
              pz  += dot4(hv, wr1[i]);
              pxh += dot4(hv, wr2[i]);
            }
          }
        } else {
          const float* aa = lds + (fam ? O_S1 : O_S0) + ks * SKS + ro * SRS;
          #pragma unroll
          for (int i = 0; i < 8; ++i) {
            const float4 av = F4(aa + i * 4);
            pr += dot4(av, wr0[i]);
            pz += dot4(av, wr1[i]);
            if (fam) pxh += dot4(av, wr2[i]);
            else     pxi += dot4(av, wr2[i]);
          }
        }
        prr[r] = pr; pzz[r] = pz; pni[r] = pxi; pnh[r] = pxh;
      }
      #pragma unroll
      for (int r = 0; r < 8; ++r) { prr[r] = red8(prr[r]); pzz[r] = red8(pzz[r]); }
      if (lay == 0 && fam == 0) {
        #pragma unroll
        for (int r = 0; r < 8; ++r) { pni[r] = red8(pni[r]); pnh[r] = red8(pnh[r]); }
      } else if (fam == 0) {
        #pragma unroll
        for (int r = 0; r < 8; ++r) pni[r] = red8(pni[r]);
      } else {
        #pragma unroll
        for (int r = 0; r < 8; ++r) pnh[r] = red8(pnh[r]);
      }
      if (ks == 0) {
        #pragma unroll
        for (int r = 0; r < 8; ++r) {
          float* pb = lds + O_PB + ((wave >> 1) * 16 + rh * 8 + r) * SRS + ju;
          pb[0] = prr[r]; pb[8] = pzz[r];
          if (lay == 0 && fam == 0) { pb[16] = pni[r]; pb[24] = pnh[r]; }
          else if (fam == 0)          pb[16] = pni[r];
          else                        pb[24] = pnh[r];
        }
      }
    }
    __syncthreads();

    // finish: gates + tagged publish
    if (tid < 256) {
      const int layf = tid >> 7;
      const bool act = layf ? (s >= 1) : (s < kT);
      if (act) {
        const int rof = (tid >> 3) & 15, uf = tid & 7, jf = j0 + uf;
        const float* p0 = lds + O_PB + ((layf * 2) * 16 + rof) * SRS + uf;
        const float* p1 = p0 + 16 * SRS;
        const float rr = sigf(p0[0] + p1[0] + fb_r);
        const float zz = sigf(p0[8] + p1[8] + fb_z);
        const float nn = tanhf(p0[16] + p1[16] + fb_ni +
                               rr * (p0[24] + p1[24] + fb_nh));
        const float hp = lds[(layf ? O_S1 : O_S0) +
                             (jf >> 5) * SKS + rof * SRS + (jf & 31)];
        const float hv = (1.f - zz) * nn + zz * hp;
        // tag: h0(s) -> (s+1)&3 in slot s%3; h1(s-1) -> s&3 in slot (s-1)%3
        const int slot = layf ? ((s - 1) % 3) : (s % 3);
        const unsigned tag = layf ? (unsigned)(s & 3) : (unsigned)((s + 1) & 3);
        const unsigned bits = (__float_as_uint(hv) & ~3u) | tag;
        unsigned* hw = (layf ? h1w : h0w) + (size_t)slot * kBH +
                       (size_t)(r0 + rof) * kH + jf;
        __hip_atomic_store(hw, bits, __ATOMIC_RELAXED,
                           __HIP_MEMORY_SCOPE_AGENT);
      }
    }
    __syncthreads();   // LDS stage/partials safe for next step's writes
  }

  // ---- FC epilogue: group's WG0; h1(T-1) in slot (kT-1)%3, tag kT&3=0 ----
  if (wg == 0 && tid < 256) {
    const int rv = tid >> 4, o = (tid >> 3) & 1, kseg = tid & 7;
    const unsigned* hf = h1w + (size_t)((kT - 1) % 3) * kBH +
                         (size_t)(r0 + rv) * kH;
    const float* wfc = fcw + (size_t)o * kH;
    float acc = 0.f;
    for (int k = kseg * 32; k < kseg * 32 + 32; ++k) {
      unsigned b;
      do {
        b = __hip_atomic_load(hf + k, __ATOMIC_RELAXED,
                              __HIP_MEMORY_SCOPE_AGENT);
      } while ((b & 3u) != (unsigned)(kT & 3));
      acc += fmaxf(__uint_as_float(b), 0.f) * wfc[k];
    }
    acc += __shfl_xor(acc, 1);
    acc += __shfl_xor(acc, 2);
    acc += __shfl_xor(acc, 4);
    if (kseg == 0) out[(r0 + rv) * 2 + o] = acc + fcb[o];
  }
}

extern "C" void kernel_launch(void* const* d_in, const int* in_sizes, int n_in,
                              void* d_out, int out_size, void* d_ws, size_t ws_size,
                              hipStream_t stream) {
  const float* x    = (const float*)d_in[0];
  const float* wih0 = (const float*)d_in[1];
  const float* whh0 = (const float*)d_in[2];
  const float* bih0 = (const float*)d_in[3];
  const float* bhh0 = (const float*)d_in[4];
  const float* wih1 = (const float*)d_in[5];
  const float* whh1 = (const float*)d_in[6];
  const float* bih1 = (const float*)d_in[7];
  const float* bhh1 = (const float*)d_in[8];
  const float* fcw  = (const float*)d_in[9];
  const float* fcb  = (const float*)d_in[10];

  unsigned* h0w = (unsigned*)d_ws;                 // [3][B][H] tagged
  unsigned* h1w = h0w + 3 * kBH;                   // [3][B][H] tagged
  unsigned* sd  = h1w + 3 * kBH;                   // [NWG][FS]
  float* out = (float*)d_out;

  // zero both tagged h buffers (tag 0 == t=-1) + stage_done flags
  hipMemsetAsync(d_ws, 0,
                 (size_t)(6 * kBH) * sizeof(unsigned) +
                 (size_t)NWG * FS * sizeof(unsigned), stream);

  gru_persistent<<<NWG, NT, 0, stream>>>(
      x, wih0, whh0, bih0, bhh0, wih1, whh1, bih1, bhh1,
      fcw, fcb, h0w, h1w, sd, out);
}